// Round 7
// baseline (127.985 us; speedup 1.0000x reference)
//
#include <hip/hip_runtime.h>

#define NH   8192
#define DIM  256
#define NTOT 16384
#define TILE 128
#define NB   (NTOT / TILE)        // 128
#define NTRI (NB * (NB + 1) / 2)  // 8256
#define TRIOFF(x) ((x) * (2 * NB + 1 - (x)) / 2)  // x*(257-x)/2

constexpr float GAMMA = 0.00390625f; // 1/256

using short4v = __attribute__((ext_vector_type(4))) short;
using half8   = __attribute__((ext_vector_type(8))) _Float16;
using f32x4   = __attribute__((ext_vector_type(4))) float;

// ---------------- fused convert (fp32 -> f16) + exact fp32 row norms ----------------
__global__ void prep_kernel(const float* __restrict__ zs,
                            const float* __restrict__ zt,
                            unsigned short* __restrict__ Zf,
                            float* __restrict__ n2) {
    int w = threadIdx.x >> 6, l = threadIdx.x & 63;
    int row = blockIdx.x * 4 + w;
    const float* zp = (row < NH) ? zs + (size_t)row * DIM
                                 : zt + (size_t)(row - NH) * DIM;
    float4 v = *(const float4*)(zp + l * 4);
    float s = v.x * v.x + v.y * v.y + v.z * v.z + v.w * v.w;
#pragma unroll
    for (int off = 32; off; off >>= 1) s += __shfl_xor(s, off);
    if (l == 0) n2[row] = s;

    float x[4] = {v.x, v.y, v.z, v.w};
    short4v hv;
#pragma unroll
    for (int j = 0; j < 4; ++j) {
        _Float16 h = (_Float16)x[j];          // RNE
        hv[j] = *(short*)&h;
    }
    *(short4v*)(Zf + (size_t)row * DIM + l * 4) = hv;
}

// ---------------- main: 128x128 tiles, 4 waves, f16 MFMA, dbuf LDS, 4+ blocks/CU ----------------
__global__ __launch_bounds__(256, 4)
void mmd_mfma_kernel(const unsigned short* __restrict__ Zf,
                     const float* __restrict__ n2,
                     double* __restrict__ partial) {
    // 2 buffers x {A 128x32, B 128x32} f16 = 32 KB
    __shared__ __align__(16) unsigned short lds[2][8192];

    const int tid = threadIdx.x;
    const int w = tid >> 6, l = tid & 63;
    const int wr = w >> 1, wc = w & 1;   // 2x2 wave grid; wave owns 64x64
    const int fr = l & 15;               // fragment row/col within 16
    const int g  = l >> 4;               // k-group 0..3

    // XCD-aware bijective swizzle (8256 % 8 == 0)
    int t = ((int)blockIdx.x & 7) * (NTRI / 8) + ((int)blockIdx.x >> 3);

    // linear t -> upper-triangle (r, c), r <= c
    int r = (int)((257.0 - sqrt(257.0 * 257.0 - 8.0 * (double)t)) * 0.5);
    if (r < 0) r = 0;
    if (r > NB - 1) r = NB - 1;
    while (r < NB - 1 && TRIOFF(r + 1) <= t) ++r;
    while (r > 0 && TRIOFF(r) > t) --r;
    const int c = r + (t - TRIOFF(r));
    const int xbase = r * TILE, ybase = c * TILE;

    const unsigned short* gA = Zf + (size_t)xbase * DIM;
    const unsigned short* gB = Zf + (size_t)ybase * DIM;

    // fragment reads: slot' = g ^ ((fr>>1)&3)   (verified conflict-free R2/R3/R6)
    const int slotp = g ^ ((fr >> 1) & 3);
    const int aoff = (wr * 64 + fr) * 32 + slotp * 8;           // + m*512
    const int boff = 4096 + (wc * 64 + fr) * 32 + slotp * 8;    // + n*512

    f32x4 acc[4][4];
#pragma unroll
    for (int m = 0; m < 4; ++m)
#pragma unroll
        for (int n = 0; n < 4; ++n) acc[m][n] = {0.f, 0.f, 0.f, 0.f};

    // staging: linear LDS dest (tid*16B), pre-swizzled global source slot
#define STAGE(KC, P)                                                                 \
    {                                                                                \
        _Pragma("unroll")                                                            \
        for (int q = 0; q < 2; ++q) { /* A: 512 x 16B */                             \
            const int idx = q * 256 + tid;                                           \
            const int row = idx >> 2;                                                \
            const int slot = (idx & 3) ^ ((row >> 1) & 3);                           \
            const unsigned short* src = gA + (size_t)row * DIM + (KC) + slot * 8;    \
            __builtin_amdgcn_global_load_lds(src, &lds[P][idx * 8], 16, 0, 0);       \
        }                                                                            \
        _Pragma("unroll")                                                            \
        for (int q = 0; q < 2; ++q) { /* B: 512 x 16B */                             \
            const int idx = q * 256 + tid;                                           \
            const int row = idx >> 2;                                                \
            const int slot = (idx & 3) ^ ((row >> 1) & 3);                           \
            const unsigned short* src = gB + (size_t)row * DIM + (KC) + slot * 8;    \
            __builtin_amdgcn_global_load_lds(src, &lds[P][4096 + idx * 8], 16, 0, 0);\
        }                                                                            \
    }

    STAGE(0, 0);
    __syncthreads();

    for (int ch = 0; ch < 8; ++ch) {
        const int p = ch & 1;
        if (ch < 7) STAGE((ch + 1) * 32, p ^ 1);

        half8 bq[4];
#pragma unroll
        for (int n = 0; n < 4; ++n) bq[n] = *(const half8*)&lds[p][boff + n * 512];
        __builtin_amdgcn_s_setprio(1);
#pragma unroll
        for (int m = 0; m < 4; ++m) {
            half8 aq = *(const half8*)&lds[p][aoff + m * 512];
#pragma unroll
            for (int n = 0; n < 4; ++n)
                acc[m][n] = __builtin_amdgcn_mfma_f32_16x16x32_f16(aq, bq[n], acc[m][n], 0, 0, 0);
        }
        __builtin_amdgcn_s_setprio(0);
        __syncthreads();  // reads of lds[p] done; stage into lds[p^1] drained
    }

    // epilogue: exp(-g*d2) = exp2(K2*dot - cx - cy),  K2 = 2*g*log2e, cx = g*log2e*|x|^2
    // C/D layout: col = lane&15 (fr), row = (lane>>4)*4 + reg   (verified R2/R3/R6)
    const float GL2E = GAMMA * 1.4426950408889634f;
    const float K2   = 2.0f * GL2E;
    float cy[4];
    int   gjs[4];
#pragma unroll
    for (int n = 0; n < 4; ++n) {
        gjs[n] = ybase + wc * 64 + n * 16 + fr;
        cy[n]  = GL2E * n2[gjs[n]];
    }
    float fsum = 0.0f;
    if (r != c) {  // strictly above diagonal: uniform weight 2
#pragma unroll
        for (int m = 0; m < 4; ++m) {
#pragma unroll
            for (int j = 0; j < 4; ++j) {
                float cx = GL2E * n2[xbase + wr * 64 + m * 16 + g * 4 + j];
#pragma unroll
                for (int n = 0; n < 4; ++n)
                    fsum += exp2f(fmaf(K2, acc[m][n][j], -cx) - cy[n]);
            }
        }
        fsum *= 2.0f;
    } else {  // diagonal tile: i<j -> 2, i==j -> 1, i>j -> 0
#pragma unroll
        for (int m = 0; m < 4; ++m) {
#pragma unroll
            for (int j = 0; j < 4; ++j) {
                const int gi = xbase + wr * 64 + m * 16 + g * 4 + j;
                float cx = GL2E * n2[gi];
#pragma unroll
                for (int n = 0; n < 4; ++n) {
                    float e = exp2f(fmaf(K2, acc[m][n][j], -cx) - cy[n]);
                    float wgt = (gi < gjs[n]) ? 2.0f : ((gi == gjs[n]) ? 1.0f : 0.0f);
                    fsum += wgt * e;
                }
            }
        }
    }

#pragma unroll
    for (int off = 32; off; off >>= 1) fsum += __shfl_xor(fsum, off);

    __syncthreads();
    double* wsum = (double*)&lds[0][0];
    if (l == 0) wsum[w] = (double)fsum;
    __syncthreads();
    if (tid == 0) {
        double tot = wsum[0] + wsum[1] + wsum[2] + wsum[3];
        double sgn = ((xbase < NH) == (ybase < NH)) ? 1.0 : -1.0;
        partial[blockIdx.x] = sgn * tot;
    }
}

// ---------------- final reduce ----------------
__global__ void reduce_partials_kernel(const double* __restrict__ partial,
                                       float* __restrict__ out) {
    __shared__ double ws[4];
    double s = 0.0;
    for (int i = threadIdx.x; i < NTRI; i += 256) s += partial[i];
#pragma unroll
    for (int off = 32; off; off >>= 1) s += __shfl_xor(s, off);
    if ((threadIdx.x & 63) == 0) ws[threadIdx.x >> 6] = s;
    __syncthreads();
    if (threadIdx.x == 0) {
        double tot = ws[0] + ws[1] + ws[2] + ws[3];
        out[0] = (float)(tot / ((double)NH * (double)NH));
    }
}

extern "C" void kernel_launch(void* const* d_in, const int* in_sizes, int n_in,
                              void* d_out, int out_size, void* d_ws, size_t ws_size,
                              hipStream_t stream) {
    const float* zs = (const float*)d_in[0];
    const float* zt = (const float*)d_in[1];
    float* out = (float*)d_out;

    unsigned short* Zf = (unsigned short*)d_ws;                  // 8 MB (f16)
    float*  n2      = (float*)((char*)d_ws + 8388608);           // 64 KB
    double* partial = (double*)((char*)d_ws + 8454144);          // 66 KB

    prep_kernel<<<NTOT / 4, 256, 0, stream>>>(zs, zt, Zf, n2);
    mmd_mfma_kernel<<<NTRI, 256, 0, stream>>>(Zf, n2, partial);
    reduce_partials_kernel<<<1, 256, 0, stream>>>(partial, out);
}

// Round 9
// 103.246 us; speedup vs baseline: 1.2396x; 1.2396x over previous
//
#include <hip/hip_runtime.h>

#define NH   8192
#define DIM  256
#define NTOT 16384
#define TM   256                  // tile rows
#define TN   128                  // tile cols
#define NRB  64                   // row blocks
// kept tiles: C >= 2R; F(R) = R*(129-R); total = 4160
#define NTILES 4160
#define FCUM(R) ((R) * (129 - (R)))

constexpr float GAMMA = 0.00390625f; // 1/256

using short4v = __attribute__((ext_vector_type(4))) short;
using half8   = __attribute__((ext_vector_type(8))) _Float16;
using f32x4   = __attribute__((ext_vector_type(4))) float;

// ---------------- fused convert (fp32 -> f16) + exact fp32 row norms ----------------
__global__ void prep_kernel(const float* __restrict__ zs,
                            const float* __restrict__ zt,
                            unsigned short* __restrict__ Zf,
                            float* __restrict__ n2) {
    int w = threadIdx.x >> 6, l = threadIdx.x & 63;
    int row = blockIdx.x * 4 + w;
    const float* zp = (row < NH) ? zs + (size_t)row * DIM
                                 : zt + (size_t)(row - NH) * DIM;
    float4 v = *(const float4*)(zp + l * 4);
    float s = v.x * v.x + v.y * v.y + v.z * v.z + v.w * v.w;
#pragma unroll
    for (int off = 32; off; off >>= 1) s += __shfl_xor(s, off);
    if (l == 0) n2[row] = s;

    float x[4] = {v.x, v.y, v.z, v.w};
    short4v hv;
#pragma unroll
    for (int j = 0; j < 4; ++j) {
        _Float16 h = (_Float16)x[j];          // RNE
        hv[j] = *(short*)&h;
    }
    *(short4v*)(Zf + (size_t)row * DIM + l * 4) = hv;
}

// ---------------- main: 256x128 tiles, 4 waves, f16 MFMA ----------------
// 3-buffer LDS rotation, depth-2 prefetch, counted vmcnt + raw s_barrier (T3/T4)
__global__ __launch_bounds__(256, 2)
void mmd_mfma_kernel(const unsigned short* __restrict__ Zf,
                     const float* __restrict__ n2,
                     double* __restrict__ partial) {
    // 3 buffers x {A 256x32, B 128x32} f16 = 3 x 24 KB = 72 KB
    __shared__ __align__(16) unsigned short lds[3][12288];

    const int tid = threadIdx.x;
    const int w = tid >> 6, l = tid & 63;
    const int wr = w >> 1, wc = w & 1;   // 2x2 wave grid; wave owns 128x64
    const int fr = l & 15;               // fragment row/col within 16
    const int g  = l >> 4;               // k-group 0..3

    // XCD-aware bijective swizzle (4160 % 8 == 0)
    int t = ((int)blockIdx.x & 7) * (NTILES / 8) + ((int)blockIdx.x >> 3);

    // t -> (R, C): largest R with F(R) <= t ; C = 2R + (t - F(R))
    int R = (int)((129.0 - sqrt(129.0 * 129.0 - 4.0 * (double)t)) * 0.5);
    if (R < 0) R = 0;
    if (R > NRB - 1) R = NRB - 1;
    while (R < NRB - 1 && FCUM(R + 1) <= t) ++R;
    while (R > 0 && FCUM(R) > t) --R;
    const int C = 2 * R + (t - FCUM(R));
    const int xbase = R * TM, ybase = C * TN;
    const bool straddle = (C <= 2 * R + 1);  // tile touches/crosses the diagonal

    const unsigned short* gA = Zf + (size_t)xbase * DIM;
    const unsigned short* gB = Zf + (size_t)ybase * DIM;

    // fragment reads: slot' = g ^ ((fr>>1)&3)   (verified conflict-free R2/R3/R6/R7)
    const int slotp = g ^ ((fr >> 1) & 3);
    const int aoff = (wr * 128 + fr) * 32 + slotp * 8;          // + m*512
    const int boff = 8192 + (wc * 64 + fr) * 32 + slotp * 8;    // + n*512

    f32x4 acc[8][4];
#pragma unroll
    for (int m = 0; m < 8; ++m)
#pragma unroll
        for (int n = 0; n < 4; ++n) acc[m][n] = {0.f, 0.f, 0.f, 0.f};

    // staging: linear LDS dest (tid*16B), pre-swizzled global source slot
    // 6 global_load_lds per thread per STAGE (A: 4, B: 2)
#define STAGE(KC, P)                                                                 \
    {                                                                                \
        _Pragma("unroll")                                                            \
        for (int q = 0; q < 4; ++q) { /* A: 1024 x 16B */                            \
            const int idx = q * 256 + tid;                                           \
            const int row = idx >> 2;                                                \
            const int slot = (idx & 3) ^ ((row >> 1) & 3);                           \
            const unsigned short* src = gA + (size_t)row * DIM + (KC) + slot * 8;    \
            __builtin_amdgcn_global_load_lds(src, &lds[P][idx * 8], 16, 0, 0);       \
        }                                                                            \
        _Pragma("unroll")                                                            \
        for (int q = 0; q < 2; ++q) { /* B: 512 x 16B */                             \
            const int idx = q * 256 + tid;                                           \
            const int row = idx >> 2;                                                \
            const int slot = (idx & 3) ^ ((row >> 1) & 3);                           \
            const unsigned short* src = gB + (size_t)row * DIM + (KC) + slot * 8;    \
            __builtin_amdgcn_global_load_lds(src, &lds[P][8192 + idx * 8], 16, 0, 0);\
        }                                                                            \
    }

    STAGE(0, 0);
    STAGE(32, 1);

#pragma unroll
    for (int ch = 0; ch < 8; ++ch) {
        const int p = ch % 3;
        if (ch < 6) {
            STAGE((ch + 2) * 32, (ch + 2) % 3);  // depth-2 prefetch
            asm volatile("s_waitcnt vmcnt(12)" ::: "memory");  // chunk ch landed; 12 newer in flight
        } else if (ch == 6) {
            asm volatile("s_waitcnt vmcnt(6)" ::: "memory");
        } else {
            asm volatile("s_waitcnt vmcnt(0)" ::: "memory");
        }
        __builtin_amdgcn_s_barrier();  // all waves' chunk-ch data resident

        half8 bq[4];
#pragma unroll
        for (int n = 0; n < 4; ++n) bq[n] = *(const half8*)&lds[p][boff + n * 512];
        __builtin_amdgcn_s_setprio(1);
#pragma unroll
        for (int m = 0; m < 8; ++m) {
            half8 aq = *(const half8*)&lds[p][aoff + m * 512];
#pragma unroll
            for (int n = 0; n < 4; ++n)
                acc[m][n] = __builtin_amdgcn_mfma_f32_16x16x32_f16(aq, bq[n], acc[m][n], 0, 0, 0);
        }
        __builtin_amdgcn_s_setprio(0);
        __builtin_amdgcn_s_barrier();  // all waves done reading lds[p] before its rewrite
    }

    // epilogue: exp(-g*d2) = exp2(K2*dot - cx - cy);  __builtin_amdgcn_exp2f -> v_exp_f32
    // C/D layout: col = lane&15 (fr), row = (lane>>4)*4 + reg   (verified R2..R7)
    const float GL = GAMMA * 1.4426950408889634f;  // gamma*log2(e)
    const float K2 = 2.0f * GL;
    float ncy[4];
    int   gjs[4];
#pragma unroll
    for (int n = 0; n < 4; ++n) {
        gjs[n] = ybase + wc * 64 + n * 16 + fr;
        ncy[n] = -GL * n2[gjs[n]];
    }
    float fsum;
    if (!straddle) {  // strictly above diagonal: uniform weight 2
        float fs0 = 0.f, fs1 = 0.f, fs2 = 0.f, fs3 = 0.f;  // break serial add chain
#pragma unroll
        for (int m = 0; m < 8; ++m) {
#pragma unroll
            for (int j = 0; j < 4; ++j) {
                float cx = GL * n2[xbase + wr * 128 + m * 16 + g * 4 + j];
                fs0 += __builtin_amdgcn_exp2f(fmaf(K2, acc[m][0][j], ncy[0]) - cx);
                fs1 += __builtin_amdgcn_exp2f(fmaf(K2, acc[m][1][j], ncy[1]) - cx);
                fs2 += __builtin_amdgcn_exp2f(fmaf(K2, acc[m][2][j], ncy[2]) - cx);
                fs3 += __builtin_amdgcn_exp2f(fmaf(K2, acc[m][3][j], ncy[3]) - cx);
            }
        }
        fsum = ((fs0 + fs1) + (fs2 + fs3)) * 2.0f;
    } else {  // diagonal-straddling tile: i<j -> 2, i==j -> 1, i>j -> 0
        fsum = 0.f;
#pragma unroll
        for (int m = 0; m < 8; ++m) {
#pragma unroll
            for (int j = 0; j < 4; ++j) {
                const int gi = xbase + wr * 128 + m * 16 + g * 4 + j;
                float cx = GL * n2[gi];
#pragma unroll
                for (int n = 0; n < 4; ++n) {
                    float e = __builtin_amdgcn_exp2f(fmaf(K2, acc[m][n][j], ncy[n]) - cx);
                    float wgt = (gi < gjs[n]) ? 2.0f : ((gi == gjs[n]) ? 1.0f : 0.0f);
                    fsum += wgt * e;
                }
            }
        }
    }

#pragma unroll
    for (int off = 32; off; off >>= 1) fsum += __shfl_xor(fsum, off);

    __syncthreads();
    double* wsum = (double*)&lds[0][0];
    if (l == 0) wsum[w] = (double)fsum;
    __syncthreads();
    if (tid == 0) {
        double tot = wsum[0] + wsum[1] + wsum[2] + wsum[3];
        double sgn = ((xbase < NH) == (ybase < NH)) ? 1.0 : -1.0;
        partial[blockIdx.x] = sgn * tot;
    }
}

// ---------------- final reduce ----------------
__global__ void reduce_partials_kernel(const double* __restrict__ partial,
                                       float* __restrict__ out) {
    __shared__ double ws[4];
    double s = 0.0;
    for (int i = threadIdx.x; i < NTILES; i += 256) s += partial[i];
#pragma unroll
    for (int off = 32; off; off >>= 1) s += __shfl_xor(s, off);
    if ((threadIdx.x & 63) == 0) ws[threadIdx.x >> 6] = s;
    __syncthreads();
    if (threadIdx.x == 0) {
        double tot = ws[0] + ws[1] + ws[2] + ws[3];
        out[0] = (float)(tot / ((double)NH * (double)NH));
    }
}

extern "C" void kernel_launch(void* const* d_in, const int* in_sizes, int n_in,
                              void* d_out, int out_size, void* d_ws, size_t ws_size,
                              hipStream_t stream) {
    const float* zs = (const float*)d_in[0];
    const float* zt = (const float*)d_in[1];
    float* out = (float*)d_out;

    unsigned short* Zf = (unsigned short*)d_ws;                  // 8 MB (f16)
    float*  n2      = (float*)((char*)d_ws + 8388608);           // 64 KB
    double* partial = (double*)((char*)d_ws + 8454144);          // 33 KB

    prep_kernel<<<NTOT / 4, 256, 0, stream>>>(zs, zt, Zf, n2);
    mmd_mfma_kernel<<<NTILES, 256, 0, stream>>>(Zf, n2, partial);
    reduce_partials_kernel<<<1, 256, 0, stream>>>(partial, out);
}